// Round 12
// baseline (409.179 us; speedup 1.0000x reference)
//
#include <hip/hip_runtime.h>

#define EMBED 512
#define LATENT 32
#define SEQ 2048
#define MTOT 4096
#define VOCAB 32000

typedef float f32x4 __attribute__((ext_vector_type(4)));
typedef short s16x8 __attribute__((ext_vector_type(8)));

__device__ __forceinline__ unsigned short f2bf(float f) {
  unsigned u = __float_as_uint(f);
  u += 0x7FFFu + ((u >> 16) & 1u);
  return (unsigned short)(u >> 16);
}

// ---------------- downscale: lat = in @ Wd + bd (4 streams) -----------------
__global__ __launch_bounds__(256) void k_downscale(
    const float* __restrict__ Q, const float* __restrict__ K,
    const float* __restrict__ V, const float* __restrict__ X,
    const float* __restrict__ Wd, const float* __restrict__ bd,
    float* __restrict__ latq, float* __restrict__ latk,
    float* __restrict__ latv, float* __restrict__ latx) {
  __shared__ float wdT[32][516];
  const float* in; float* out;
  switch (blockIdx.y) {
    case 0: in = Q; out = latq; break;
    case 1: in = K; out = latk; break;
    case 2: in = V; out = latv; break;
    default: in = X; out = latx; break;
  }
  int t = threadIdx.x;
#pragma unroll
  for (int j = 0; j < 16; ++j) {
    int q = t * 64 + j * 4;  // flat index into Wd [512][32]
    f32x4 v = *(const f32x4*)(Wd + q);
    int k = q >> 5, c = q & 31;
    wdT[c + 0][k] = v.x;
    wdT[c + 1][k] = v.y;
    wdT[c + 2][k] = v.z;
    wdT[c + 3][k] = v.w;
  }
  __syncthreads();
  int r = t >> 5, c = t & 31;
  int row = blockIdx.x * 8 + r;
  const float* rowp = in + (size_t)row * EMBED;
  float acc = 0.f;
#pragma unroll 8
  for (int k = 0; k < 512; k += 4) {
    f32x4 iv = *(const f32x4*)(rowp + k);  // broadcast within half-wave
    f32x4 wv = *(const f32x4*)&wdT[c][k];
    acc += iv.x * wv.x + iv.y * wv.y + iv.z * wv.z + iv.w * wv.w;
  }
  out[(size_t)row * 32 + c] = acc + bd[c];
}

// ---------------- causal attention, Q-tiled (QT=4) -----------------
// R11 failure analysis: clamped-ternary prefetch forced vmcnt(0) inside the
// per-chunk chain (L2 latency exposed every 8 keys) and 1 query/wave gave a
// 31 cy/key serial chain. This version: each wave owns 4 consecutive queries
// (K/V loads amortized 4x, 4 independent softmax chains give ILP), and K/V
// are prefetched UNCONDITIONALLY (+2/+1 chunks, plain linear addresses, no
// select) so loads issue early and the waitcnt lands after ~250cy of compute.
// Overflow reads (<=7KB past latk/latv region ends) stay inside d_ws
// (regions contiguous) and are discarded by the causal mask.
__global__ __launch_bounds__(256) void k_attn(
    const float* __restrict__ lq, const float* __restrict__ lk,
    const float* __restrict__ lv, float* __restrict__ ctx) {
  int lane = threadIdx.x & 63;
  int w = threadIdx.x >> 6;
  int bl = blockIdx.x;  // 0..255
  int tile;             // 0..1023 (QT=4 queries per tile; 512 tiles/batch)
  switch (w) {          // long/short pairing per block
    case 0: tile = bl; break;
    case 1: tile = 511 - bl; break;
    case 2: tile = 512 + bl; break;
    default: tile = 1023 - bl; break;
  }
  int batch = tile >> 9;
  int q0 = (tile & 511) * 4;  // query row within batch
  int oct = lane & 7, grp = lane >> 3;

  const float* qb = lq + ((size_t)batch * SEQ + q0) * 32;
  f32x4 q4[4];
#pragma unroll
  for (int q = 0; q < 4; ++q) q4[q] = *(const f32x4*)(qb + q * 32 + oct * 4);

  const char* kp = (const char*)(lk + (size_t)batch * SEQ * 32) + lane * 16;
  const char* vp = (const char*)(lv + (size_t)batch * SEQ * 32) + lane * 16;

  const float scale = 0.17677669529663687f;  // 1/sqrt(32)
  float m[4], ssum[4];
  f32x4 ca[4];
#pragma unroll
  for (int q = 0; q < 4; ++q) {
    m[q] = -INFINITY; ssum[q] = 0.f;
    ca[q] = f32x4{0.f, 0.f, 0.f, 0.f};
  }

  int nIter = ((q0 + 3) >> 3) + 1;  // chunks of 8 keys (one per group)

  f32x4 kcur = *(const f32x4*)(kp);
  f32x4 knxt = *(const f32x4*)(kp + 1024);
  f32x4 vcur = *(const f32x4*)(vp);

  for (int it = 0; it < nIter; ++it) {
    // unconditional prefetch: linear addresses, no data-dependent select
    f32x4 k2 = *(const f32x4*)(kp + (size_t)(it + 2) * 1024);
    f32x4 v1 = *(const f32x4*)(vp + (size_t)(it + 1) * 1024);
    int j = it * 8 + grp;
#pragma unroll
    for (int q = 0; q < 4; ++q) {
      f32x4 pp = q4[q] * kcur;
      float s = pp.x + pp.y + pp.z + pp.w;
      s += __shfl_xor(s, 1, 64);  // reduce over octs within group
      s += __shfl_xor(s, 2, 64);
      s += __shfl_xor(s, 4, 64);
      s *= scale;
      if (j <= q0 + q) {  // causal mask (garbage overflow keys land here too)
        float mn = fmaxf(m[q], s);
        float f = __expf(m[q] - mn);  // exp(-inf)=0 on first valid key
        float p = __expf(s - mn);
        ssum[q] = ssum[q] * f + p;
        ca[q] = ca[q] * f + p * vcur;
        m[q] = mn;
      }
    }
    kcur = knxt; knxt = k2; vcur = v1;
  }

  // merge the 8 groups, per query
#pragma unroll
  for (int q = 0; q < 4; ++q) {
    float M = m[q];
    M = fmaxf(M, __shfl_xor(M, 8, 64));
    M = fmaxf(M, __shfl_xor(M, 16, 64));
    M = fmaxf(M, __shfl_xor(M, 32, 64));
    float sc = (m[q] == -INFINITY) ? 0.f : __expf(m[q] - M);
    float ss = ssum[q] * sc;
    f32x4 c = ca[q] * sc;
    ss += __shfl_xor(ss, 8, 64);
    ss += __shfl_xor(ss, 16, 64);
    ss += __shfl_xor(ss, 32, 64);
#pragma unroll
    for (int off = 8; off <= 32; off <<= 1) {
      c.x += __shfl_xor(c.x, off, 64);
      c.y += __shfl_xor(c.y, off, 64);
      c.z += __shfl_xor(c.z, off, 64);
      c.w += __shfl_xor(c.w, off, 64);
    }
    if (grp == 0) {  // 8 lanes x 16B = contiguous 128B row
      float inv = 1.f / ss;
      *(f32x4*)(ctx + ((size_t)batch * SEQ + q0 + q) * 32 + oct * 4) = c * inv;
    }
  }
}

// -------- upscale + tile(ctx x16) + LayerNorm -> bf16 enc --------
__global__ __launch_bounds__(512) void k_upln(
    const float* __restrict__ ctx, const float* __restrict__ latx,
    const float* __restrict__ Wu, const float* __restrict__ bu,
    const float* __restrict__ gamma, const float* __restrict__ beta,
    unsigned short* __restrict__ encb) {
  int r = blockIdx.x;
  int c = threadIdx.x;  // 0..511
  float acc = bu[c] + ctx[(size_t)r * 32 + (c & 31)];
  const float* lx = latx + (size_t)r * 32;
#pragma unroll
  for (int k = 0; k < 32; ++k) acc += lx[k] * Wu[k * EMBED + c];
  int lane = threadIdx.x & 63, w = threadIdx.x >> 6;
  float s1 = acc, s2 = acc * acc;
#pragma unroll
  for (int off = 32; off > 0; off >>= 1) {
    s1 += __shfl_xor(s1, off, 64);
    s2 += __shfl_xor(s2, off, 64);
  }
  __shared__ float r1[8], r2[8];
  if (lane == 0) { r1[w] = s1; r2[w] = s2; }
  __syncthreads();
  float t1 = 0.f, t2 = 0.f;
#pragma unroll
  for (int i = 0; i < 8; ++i) { t1 += r1[i]; t2 += r2[i]; }
  float mu = t1 * (1.f / 512.f);
  float var = t2 * (1.f / 512.f) - mu * mu;
  float rstd = rsqrtf(var + 1e-5f);
  float o = (acc - mu) * rstd * gamma[c] + beta[c];
  encb[(size_t)r * EMBED + c] = f2bf(o);
}

// -------- transpose + cast Wf [512][32000] f32 -> WfT [32000][512] bf16 -----
__global__ __launch_bounds__(256) void k_transcast(
    const float* __restrict__ Wf, unsigned short* __restrict__ wfT) {
  __shared__ float tile[64][65];
  int n0 = blockIdx.x * 64;
  int k0 = blockIdx.y * 64;
  int t = threadIdx.x;
  int rr = t >> 4;         // 0..15
  int cq = (t & 15) << 2;  // 0..60
#pragma unroll
  for (int p = 0; p < 4; ++p) {
    int kr = p * 16 + rr;
    f32x4 v = *(const f32x4*)(Wf + (size_t)(k0 + kr) * VOCAB + n0 + cq);
    tile[kr][cq + 0] = v.x;
    tile[kr][cq + 1] = v.y;
    tile[kr][cq + 2] = v.z;
    tile[kr][cq + 3] = v.w;
  }
  __syncthreads();
#pragma unroll
  for (int p = 0; p < 4; ++p) {
    int nr = p * 16 + rr;
    ushort4 u;
    u.x = f2bf(tile[cq + 0][nr]);
    u.y = f2bf(tile[cq + 1][nr]);
    u.z = f2bf(tile[cq + 2][nr]);
    u.w = f2bf(tile[cq + 3][nr]);
    *(ushort4*)(wfT + (size_t)(n0 + nr) * EMBED + k0 + cq) = u;
  }
}

// ===== final GEMM: byte-identical to round 9 (keeper) =======================
__device__ __forceinline__ void mfma16x16x32(f32x4& d, s16x8 a, s16x8 b) {
  asm("v_mfma_f32_16x16x32_bf16 %0, %1, %2, %0" : "+v"(d) : "v"(a), "v"(b));
}

__device__ __forceinline__ void gload16(const void* g, void* l) {
  __builtin_amdgcn_global_load_lds(
      (const __attribute__((address_space(1))) void*)g,
      (__attribute__((address_space(3))) void*)l, 16, 0, 0);
}

__global__ __launch_bounds__(512, 4) void k_gemm(
    const unsigned short* __restrict__ A,   // [4096][512] bf16
    const unsigned short* __restrict__ Bt,  // [32000][512] bf16
    const float* __restrict__ bias, float* __restrict__ C) {
  __shared__ char lds[2][24576];
  int tid = threadIdx.x;
  int lane = tid & 63, wave = tid >> 6;
  int wm = wave & 3, wn = wave >> 2;  // 4M x 2N wave grid
  int fr = lane & 15, fq = lane >> 4;
  int kswz = (fq ^ ((fr >> 1) & 3)) << 4;

  int id = blockIdx.x;
  int nid = (id & 7) * 500 + (id >> 3);
  int bm = nid & 15, bn = nid >> 4;
  int m0 = bm * 256, n0 = bn * 128;

  const char* Ab = (const char*)(A + (size_t)m0 * EMBED);
  const char* Bb = (const char*)(Bt + (size_t)n0 * EMBED);

  f32x4 acc[4][4];
#pragma unroll
  for (int i = 0; i < 4; ++i)
#pragma unroll
    for (int j = 0; j < 4; ++j) acc[i][j] = f32x4{0.f, 0.f, 0.f, 0.f};

  auto stage = [&](char* slot, int koff) {
#pragma unroll
    for (int i = 0; i < 2; ++i) {
      int o = i * 8192 + tid * 16;
      int row = o >> 6;
      int kb = (((o >> 4) & 3) ^ ((row >> 1) & 3)) << 4;
      gload16(Ab + (size_t)row * 1024 + koff + kb, slot + o);
    }
    int o = tid * 16;
    int row = o >> 6;
    int kb = (((o >> 4) & 3) ^ ((row >> 1) & 3)) << 4;
    gload16(Bb + (size_t)row * 1024 + koff + kb, slot + 16384 + o);
  };

  stage(&lds[0][0], 0);
  asm volatile("s_waitcnt vmcnt(0)" ::: "memory");
  __builtin_amdgcn_s_barrier();

  for (int kt = 0; kt < 16; ++kt) {
    const char* Ar = &lds[kt & 1][0];
    const char* Br = Ar + 16384;
    if (kt < 15) stage(&lds[(kt + 1) & 1][0], (kt + 1) * 64);
    s16x8 af[4];
#pragma unroll
    for (int mi = 0; mi < 4; ++mi) {
      int row = wm * 64 + mi * 16 + fr;
      af[mi] = *(const s16x8*)(Ar + row * 64 + kswz);
    }
    __builtin_amdgcn_s_setprio(1);
#pragma unroll
    for (int ni = 0; ni < 4; ++ni) {
      int row = wn * 64 + ni * 16 + fr;
      s16x8 bf = *(const s16x8*)(Br + row * 64 + kswz);
#pragma unroll
      for (int mi = 0; mi < 4; ++mi) mfma16x16x32(acc[mi][ni], af[mi], bf);
    }
    __builtin_amdgcn_s_setprio(0);
    asm volatile("s_waitcnt vmcnt(0)" ::: "memory");
    __builtin_amdgcn_s_barrier();
  }

  float* ep = (float*)&lds[0][0] + wave * 1088;  // 16 rows x 68 floats
  float bvv[4];
#pragma unroll
  for (int ni = 0; ni < 4; ++ni) bvv[ni] = bias[n0 + wn * 64 + ni * 16 + fr];
#pragma unroll
  for (int mi = 0; mi < 4; ++mi) {
#pragma unroll
    for (int ni = 0; ni < 4; ++ni)
#pragma unroll
      for (int r = 0; r < 4; ++r)
        ep[(fq * 4 + r) * 68 + ni * 16 + fr] = acc[mi][ni][r] + bvv[ni];
    __builtin_amdgcn_sched_barrier(0);
    asm volatile("s_waitcnt lgkmcnt(0)" ::: "memory");
    __builtin_amdgcn_sched_barrier(0);
#pragma unroll
    for (int p = 0; p < 4; ++p) {
      int row = p * 4 + fq;  // 0..15
      f32x4 v = *(const f32x4*)(ep + row * 68 + fr * 4);
      int m = m0 + wm * 64 + mi * 16 + row;
      __builtin_nontemporal_store(
          v, (f32x4*)(C + (size_t)m * VOCAB + n0 + wn * 64 + fr * 4));
    }
    __builtin_amdgcn_sched_barrier(0);
    asm volatile("s_waitcnt lgkmcnt(0)" ::: "memory");
    __builtin_amdgcn_sched_barrier(0);
  }
}

extern "C" void kernel_launch(void* const* d_in, const int* in_sizes, int n_in,
                              void* d_out, int out_size, void* d_ws,
                              size_t ws_size, hipStream_t stream) {
  (void)in_sizes; (void)n_in; (void)out_size; (void)ws_size;
  const float* Q = (const float*)d_in[0];
  const float* K = (const float*)d_in[1];
  const float* V = (const float*)d_in[2];
  const float* X = (const float*)d_in[3];
  const float* Wd = (const float*)d_in[4];
  const float* bd = (const float*)d_in[5];
  const float* Wu = (const float*)d_in[6];
  const float* bu = (const float*)d_in[7];
  const float* gamma = (const float*)d_in[8];
  const float* beta = (const float*)d_in[9];
  const float* Wf = (const float*)d_in[10];
  const float* bf = (const float*)d_in[11];
  float* out = (float*)d_out;
  char* ws = (char*)d_ws;
  float* latq = (float*)(ws + 0);
  float* latk = (float*)(ws + (1u << 19));
  float* latv = (float*)(ws + (2u << 19));
  float* latx = (float*)(ws + 3u * (1u << 19));
  float* ctx = (float*)(ws + (1u << 21));
  unsigned short* encb = (unsigned short*)(ws + (1u << 21) + (1u << 19));
  unsigned short* wfT =
      (unsigned short*)(ws + (1u << 21) + (1u << 19) + (1u << 22));

  k_downscale<<<dim3(512, 4), 256, 0, stream>>>(Q, K, V, X, Wd, bd, latq,
                                                latk, latv, latx);
  k_transcast<<<dim3(VOCAB / 64, EMBED / 64), 256, 0, stream>>>(Wf, wfT);
  k_attn<<<256, 256, 0, stream>>>(latq, latk, latv, ctx);
  k_upln<<<MTOT, 512, 0, stream>>>(ctx, latx, Wu, bu, gamma, beta, encb);
  k_gemm<<<4000, 512, 0, stream>>>(encb, wfT, bf, out);
}

// Round 16
// 302.768 us; speedup vs baseline: 1.3515x; 1.3515x over previous
//
#include <hip/hip_runtime.h>

#define EMBED 512
#define LATENT 32
#define SEQ 2048
#define MTOT 4096
#define VOCAB 32000

typedef float f32x4 __attribute__((ext_vector_type(4)));
typedef short s16x8 __attribute__((ext_vector_type(8)));

__device__ __forceinline__ unsigned short f2bf(float f) {
  unsigned u = __float_as_uint(f);
  u += 0x7FFFu + ((u >> 16) & 1u);
  return (unsigned short)(u >> 16);
}

__device__ __forceinline__ void mfma16x16x32(f32x4& d, s16x8 a, s16x8 b) {
  asm("v_mfma_f32_16x16x32_bf16 %0, %1, %2, %0" : "+v"(d) : "v"(a), "v"(b));
}

__device__ __forceinline__ void gload16(const void* g, void* l) {
  __builtin_amdgcn_global_load_lds(
      (const __attribute__((address_space(1))) void*)g,
      (__attribute__((address_space(3))) void*)l, 16, 0, 0);
}

// ---------------- downscale: lat = in @ Wd + bd (4 streams) -----------------
// R9 exact (f32 outputs).
__global__ __launch_bounds__(256) void k_downscale(
    const float* __restrict__ Q, const float* __restrict__ K,
    const float* __restrict__ V, const float* __restrict__ X,
    const float* __restrict__ Wd, const float* __restrict__ bd,
    float* __restrict__ latq, float* __restrict__ latk,
    float* __restrict__ latv, float* __restrict__ latx) {
  __shared__ float wdT[32][516];
  const float* in; float* out;
  switch (blockIdx.y) {
    case 0: in = Q; out = latq; break;
    case 1: in = K; out = latk; break;
    case 2: in = V; out = latv; break;
    default: in = X; out = latx; break;
  }
  int t = threadIdx.x;
#pragma unroll
  for (int j = 0; j < 16; ++j) {
    int q = t * 64 + j * 4;  // flat index into Wd [512][32]
    f32x4 v = *(const f32x4*)(Wd + q);
    int k = q >> 5, c = q & 31;
    wdT[c + 0][k] = v.x;
    wdT[c + 1][k] = v.y;
    wdT[c + 2][k] = v.z;
    wdT[c + 3][k] = v.w;
  }
  __syncthreads();
  int r = t >> 5, c = t & 31;
  int row = blockIdx.x * 8 + r;
  const float* rowp = in + (size_t)row * EMBED;
  float acc = 0.f;
#pragma unroll 8
  for (int k = 0; k < 512; k += 4) {
    f32x4 iv = *(const f32x4*)(rowp + k);  // broadcast within half-wave
    f32x4 wv = *(const f32x4*)&wdT[c][k];
    acc += iv.x * wv.x + iv.y * wv.y + iv.z * wv.z + iv.w * wv.w;
  }
  out[(size_t)row * 32 + c] = acc + bd[c];
}

// ---------------- causal attention: R9 math + LDS-staged K/V ----------------
// R9's compute is kept VERBATIM (bit-identical f32 results). Only the data
// path changes: the lane=key global scatter (64 cache lines per load instr,
// 8x TA amplification — R10 counters: hbm~0, VALUBusy 5%) is replaced by the
// GEMM-verified staging pattern: per-wave private 16KB LDS buffer, K/V
// chunks staged via global_load_lds with inverse-swizzled global source
// (G21 both-sides involution, 1KB coalesced per instr), swizzled
// ds_read_b128 readback (8-round bank spread = BW floor). Next chunk is
// staged right after lgkmcnt(0) (reads landed in regs -> buffer reusable),
// so the ~700cy flight hides under compute; vmcnt(0) only at iter end.
// Wave-private buffer -> no s_barrier anywhere.
__global__ __launch_bounds__(256) void k_attn(
    const float* __restrict__ lq, const float* __restrict__ lk,
    const float* __restrict__ lv, float* __restrict__ ctx) {
  __shared__ char kvbuf[4][16384];  // per-wave: K 8KB | V 8KB
  int lane = threadIdx.x & 63;
  int lw = threadIdx.x >> 6;
  int bl = blockIdx.x;  // 0..1023
  int qg;
  switch (lw) {
    case 0: qg = bl; break;
    case 1: qg = 2047 - bl; break;
    case 2: qg = 2048 + bl; break;
    default: qg = 4095 - bl; break;
  }
  int batch = qg >> 11;
  int qi = qg & 2047;
  const float* qp = lq + (size_t)qg * 32;
  f32x4 q4[8], ca[8];
#pragma unroll
  for (int d = 0; d < 8; ++d) {
    q4[d] = *(const f32x4*)(qp + d * 4);
    ca[d] = f32x4{0.f, 0.f, 0.f, 0.f};
  }
  const char* kbp = (const char*)(lk + (size_t)batch * SEQ * 32);
  const char* vbp = (const char*)(lv + (size_t)batch * SEQ * 32);
  char* kl = kvbuf[lw];
  char* vl = kvbuf[lw] + 8192;

  // Stage 64 K rows + 64 V rows (128B each). Dest linear (gload_lds rule);
  // source unit pre-swizzled with the SAME involution the reads apply.
  auto stage = [&](int j0) {
#pragma unroll
    for (int i = 0; i < 8; ++i) {
      int o = i * 1024 + lane * 16;
      int row = o >> 7;
      int sb = (((o >> 4) & 7) ^ (row & 7)) << 4;
      gload16(kbp + (size_t)(j0 + row) * 128 + sb, kl + o);
    }
#pragma unroll
    for (int i = 0; i < 8; ++i) {
      int o = i * 1024 + lane * 16;
      int row = o >> 7;
      int sb = (((o >> 4) & 7) ^ (row & 7)) << 4;
      gload16(vbp + (size_t)(j0 + row) * 128 + sb, vl + o);
    }
  };

  float m = -INFINITY, ssum = 0.f;
  const float scale = 0.17677669529663687f;  // 1/sqrt(32)
  int nChunk = (qi >> 6) + 1;

  stage(0);
  asm volatile("s_waitcnt vmcnt(0)" ::: "memory");

  for (int c = 0; c < nChunk; ++c) {
    // read this lane's K/V rows (row = lane), swizzle-corrected
    f32x4 kr[8], vr[8];
#pragma unroll
    for (int d = 0; d < 8; ++d) {
      int sb = (d ^ (lane & 7)) << 4;
      kr[d] = *(const f32x4*)(kl + lane * 128 + sb);
      vr[d] = *(const f32x4*)(vl + lane * 128 + sb);
    }
    // reads complete -> buffer reusable; issue next stage, hide under compute
    asm volatile("s_waitcnt lgkmcnt(0)" ::: "memory");
    __builtin_amdgcn_sched_barrier(0);
    if (c + 1 < nChunk) stage((c + 1) * 64);
    __builtin_amdgcn_sched_barrier(0);
    int j = c * 64 + lane;
    if (j <= qi) {  // R9 compute, verbatim
      f32x4 s4 = f32x4{0.f, 0.f, 0.f, 0.f};
#pragma unroll
      for (int d = 0; d < 8; ++d) s4 += q4[d] * kr[d];
      float s = (s4.x + s4.y + s4.z + s4.w) * scale;
      float mn = fmaxf(m, s);
      float f = __expf(m - mn);  // exp(-inf)=0 on first valid key
      float p = __expf(s - mn);
      ssum = ssum * f + p;
#pragma unroll
      for (int d = 0; d < 8; ++d) ca[d] = ca[d] * f + p * vr[d];
      m = mn;
    }
    if (c + 1 < nChunk)
      asm volatile("s_waitcnt vmcnt(0)" ::: "memory");  // next chunk landed
  }

  // cross-lane merge (R9 exact)
  float M = m;
#pragma unroll
  for (int off = 32; off > 0; off >>= 1) M = fmaxf(M, __shfl_xor(M, off, 64));
  float sc = (m == -INFINITY) ? 0.f : __expf(m - M);
  ssum *= sc;
#pragma unroll
  for (int off = 32; off > 0; off >>= 1) ssum += __shfl_xor(ssum, off, 64);
#pragma unroll
  for (int d = 0; d < 8; ++d) {
    ca[d] *= sc;
#pragma unroll
    for (int off = 32; off > 0; off >>= 1) {
      ca[d].x += __shfl_xor(ca[d].x, off, 64);
      ca[d].y += __shfl_xor(ca[d].y, off, 64);
      ca[d].z += __shfl_xor(ca[d].z, off, 64);
      ca[d].w += __shfl_xor(ca[d].w, off, 64);
    }
  }
  float inv = 1.f / ssum;
  float outv = 0.f;
#pragma unroll
  for (int d = 0; d < 32; ++d) {
    if (lane == d) outv = ca[d >> 2][d & 3];
  }
  if (lane < 32) ctx[(size_t)qg * 32 + lane] = outv * inv;
}

// -------- upscale + tile(ctx x16) + LayerNorm -> bf16 enc (R9 exact) --------
__global__ __launch_bounds__(512) void k_upln(
    const float* __restrict__ ctx, const float* __restrict__ latx,
    const float* __restrict__ Wu, const float* __restrict__ bu,
    const float* __restrict__ gamma, const float* __restrict__ beta,
    unsigned short* __restrict__ encb) {
  int r = blockIdx.x;
  int c = threadIdx.x;  // 0..511
  float acc = bu[c] + ctx[(size_t)r * 32 + (c & 31)];
  const float* lx = latx + (size_t)r * 32;
#pragma unroll
  for (int k = 0; k < 32; ++k) acc += lx[k] * Wu[k * EMBED + c];
  int lane = threadIdx.x & 63, w = threadIdx.x >> 6;
  float s1 = acc, s2 = acc * acc;
#pragma unroll
  for (int off = 32; off > 0; off >>= 1) {
    s1 += __shfl_xor(s1, off, 64);
    s2 += __shfl_xor(s2, off, 64);
  }
  __shared__ float r1[8], r2[8];
  if (lane == 0) { r1[w] = s1; r2[w] = s2; }
  __syncthreads();
  float t1 = 0.f, t2 = 0.f;
#pragma unroll
  for (int i = 0; i < 8; ++i) { t1 += r1[i]; t2 += r2[i]; }
  float mu = t1 * (1.f / 512.f);
  float var = t2 * (1.f / 512.f) - mu * mu;
  float rstd = rsqrtf(var + 1e-5f);
  float o = (acc - mu) * rstd * gamma[c] + beta[c];
  encb[(size_t)r * EMBED + c] = f2bf(o);
}

// -------- transpose + cast Wf -> WfT bf16 (R9 exact) -----------------------
__global__ __launch_bounds__(256) void k_transcast(
    const float* __restrict__ Wf, unsigned short* __restrict__ wfT) {
  __shared__ float tile[64][65];
  int n0 = blockIdx.x * 64;
  int k0 = blockIdx.y * 64;
  int t = threadIdx.x;
  int rr = t >> 4;         // 0..15
  int cq = (t & 15) << 2;  // 0..60
#pragma unroll
  for (int p = 0; p < 4; ++p) {
    int kr = p * 16 + rr;
    f32x4 v = *(const f32x4*)(Wf + (size_t)(k0 + kr) * VOCAB + n0 + cq);
    tile[kr][cq + 0] = v.x;
    tile[kr][cq + 1] = v.y;
    tile[kr][cq + 2] = v.z;
    tile[kr][cq + 3] = v.w;
  }
  __syncthreads();
#pragma unroll
  for (int p = 0; p < 4; ++p) {
    int nr = p * 16 + rr;
    ushort4 u;
    u.x = f2bf(tile[cq + 0][nr]);
    u.y = f2bf(tile[cq + 1][nr]);
    u.z = f2bf(tile[cq + 2][nr]);
    u.w = f2bf(tile[cq + 3][nr]);
    *(ushort4*)(wfT + (size_t)(n0 + nr) * EMBED + k0 + cq) = u;
  }
}

// ===== final GEMM: byte-identical to round 9 (keeper) =======================
__global__ __launch_bounds__(512, 4) void k_gemm(
    const unsigned short* __restrict__ A,   // [4096][512] bf16
    const unsigned short* __restrict__ Bt,  // [32000][512] bf16
    const float* __restrict__ bias, float* __restrict__ C) {
  __shared__ char lds[2][24576];
  int tid = threadIdx.x;
  int lane = tid & 63, wave = tid >> 6;
  int wm = wave & 3, wn = wave >> 2;  // 4M x 2N wave grid
  int fr = lane & 15, fq = lane >> 4;
  int kswz = (fq ^ ((fr >> 1) & 3)) << 4;

  int id = blockIdx.x;
  int nid = (id & 7) * 500 + (id >> 3);
  int bm = nid & 15, bn = nid >> 4;
  int m0 = bm * 256, n0 = bn * 128;

  const char* Ab = (const char*)(A + (size_t)m0 * EMBED);
  const char* Bb = (const char*)(Bt + (size_t)n0 * EMBED);

  f32x4 acc[4][4];
#pragma unroll
  for (int i = 0; i < 4; ++i)
#pragma unroll
    for (int j = 0; j < 4; ++j) acc[i][j] = f32x4{0.f, 0.f, 0.f, 0.f};

  auto stage = [&](char* slot, int koff) {
#pragma unroll
    for (int i = 0; i < 2; ++i) {
      int o = i * 8192 + tid * 16;
      int row = o >> 6;
      int kb = (((o >> 4) & 3) ^ ((row >> 1) & 3)) << 4;
      gload16(Ab + (size_t)row * 1024 + koff + kb, slot + o);
    }
    int o = tid * 16;
    int row = o >> 6;
    int kb = (((o >> 4) & 3) ^ ((row >> 1) & 3)) << 4;
    gload16(Bb + (size_t)row * 1024 + koff + kb, slot + 16384 + o);
  };

  stage(&lds[0][0], 0);
  asm volatile("s_waitcnt vmcnt(0)" ::: "memory");
  __builtin_amdgcn_s_barrier();

  for (int kt = 0; kt < 16; ++kt) {
    const char* Ar = &lds[kt & 1][0];
    const char* Br = Ar + 16384;
    if (kt < 15) stage(&lds[(kt + 1) & 1][0], (kt + 1) * 64);
    s16x8 af[4];
#pragma unroll
    for (int mi = 0; mi < 4; ++mi) {
      int row = wm * 64 + mi * 16 + fr;
      af[mi] = *(const s16x8*)(Ar + row * 64 + kswz);
    }
    __builtin_amdgcn_s_setprio(1);
#pragma unroll
    for (int ni = 0; ni < 4; ++ni) {
      int row = wn * 64 + ni * 16 + fr;
      s16x8 bf = *(const s16x8*)(Br + row * 64 + kswz);
#pragma unroll
      for (int mi = 0; mi < 4; ++mi) mfma16x16x32(acc[mi][ni], af[mi], bf);
    }
    __builtin_amdgcn_s_setprio(0);
    asm volatile("s_waitcnt vmcnt(0)" ::: "memory");
    __builtin_amdgcn_s_barrier();
  }

  float* ep = (float*)&lds[0][0] + wave * 1088;  // 16 rows x 68 floats
  float bvv[4];
#pragma unroll
  for (int ni = 0; ni < 4; ++ni) bvv[ni] = bias[n0 + wn * 64 + ni * 16 + fr];
#pragma unroll
  for (int mi = 0; mi < 4; ++mi) {
#pragma unroll
    for (int ni = 0; ni < 4; ++ni)
#pragma unroll
      for (int r = 0; r < 4; ++r)
        ep[(fq * 4 + r) * 68 + ni * 16 + fr] = acc[mi][ni][r] + bvv[ni];
    __builtin_amdgcn_sched_barrier(0);
    asm volatile("s_waitcnt lgkmcnt(0)" ::: "memory");
    __builtin_amdgcn_sched_barrier(0);
#pragma unroll
    for (int p = 0; p < 4; ++p) {
      int row = p * 4 + fq;  // 0..15
      f32x4 v = *(const f32x4*)(ep + row * 68 + fr * 4);
      int m = m0 + wm * 64 + mi * 16 + row;
      __builtin_nontemporal_store(
          v, (f32x4*)(C + (size_t)m * VOCAB + n0 + wn * 64 + fr * 4));
    }
    __builtin_amdgcn_sched_barrier(0);
    asm volatile("s_waitcnt lgkmcnt(0)" ::: "memory");
    __builtin_amdgcn_sched_barrier(0);
  }
}

extern "C" void kernel_launch(void* const* d_in, const int* in_sizes, int n_in,
                              void* d_out, int out_size, void* d_ws,
                              size_t ws_size, hipStream_t stream) {
  (void)in_sizes; (void)n_in; (void)out_size; (void)ws_size;
  const float* Q = (const float*)d_in[0];
  const float* K = (const float*)d_in[1];
  const float* V = (const float*)d_in[2];
  const float* X = (const float*)d_in[3];
  const float* Wd = (const float*)d_in[4];
  const float* bd = (const float*)d_in[5];
  const float* Wu = (const float*)d_in[6];
  const float* bu = (const float*)d_in[7];
  const float* gamma = (const float*)d_in[8];
  const float* beta = (const float*)d_in[9];
  const float* Wf = (const float*)d_in[10];
  const float* bf = (const float*)d_in[11];
  float* out = (float*)d_out;
  char* ws = (char*)d_ws;
  float* latq = (float*)(ws + 0);
  float* latk = (float*)(ws + (1u << 19));
  float* latv = (float*)(ws + (2u << 19));
  float* latx = (float*)(ws + 3u * (1u << 19));
  float* ctx = (float*)(ws + (1u << 21));
  unsigned short* encb = (unsigned short*)(ws + (1u << 21) + (1u << 19));
  unsigned short* wfT =
      (unsigned short*)(ws + (1u << 21) + (1u << 19) + (1u << 22));

  k_downscale<<<dim3(512, 4), 256, 0, stream>>>(Q, K, V, X, Wd, bd, latq,
                                                latk, latv, latx);
  k_transcast<<<dim3(VOCAB / 64, EMBED / 64), 256, 0, stream>>>(Wf, wfT);
  k_attn<<<1024, 256, 0, stream>>>(latq, latk, latv, ctx);
  k_upln<<<MTOT, 512, 0, stream>>>(ctx, latx, Wu, bu, gamma, beta, encb);
  k_gemm<<<4000, 512, 0, stream>>>(encb, wfT, bf, out);
}